// Round 18
// baseline (143.770 us; speedup 1.0000x reference)
//
#include <hip/hip_runtime.h>
#include <math.h>

#define B_SZ 256
#define N_SZ 200
#define NN (N_SZ * N_SZ)          // 40000
#define FIN 200
#define OUT_F 256
#define NCLS 8
#define KSEL 3980
#define NUPPER 20100              // N*(N+1)/2
#define NT 7                      // ceil(200/32) tiles per dim
#define NTILES 28                 // NT*(NT+1)/2 upper tile pairs

#define ADJ_STRIDE 224            // adj_bf16 row stride (K-padded zeros beyond 199)
#define KGRP_PB 25                // kgroups per batch (200/8)
#define XWM_PB (KGRP_PB * 2048)   // 51200 elems per batch in mfma layout

#define EMB_OFF (B_SZ * N_SZ * NCLS)               // 409600
#define ADJ_OFF (EMB_OFF + B_SZ * N_SZ * OUT_F)    // 13516800

// ---- ws layout (bytes) ----
// XW_mfma: [0, 26,214,400)        written k2 (after kAS), read k3
// w_kgrp:  [26,214,400, +114,688) bf16 w kgroup layout, 28 kgrp (3 zero)
// adjb16:  [26,329,088, +22,937,600) end 49,266,688
#define WKG_OFF_B    26214400
#define ADJB16_OFF_B 26329088

typedef unsigned short ushort_t;
typedef float f32x4 __attribute__((ext_vector_type(4)));
typedef short bf16x8 __attribute__((ext_vector_type(8)));
typedef ushort_t u16x8 __attribute__((ext_vector_type(8)));

__device__ __forceinline__ unsigned sortkey(float f) {
    unsigned u = __float_as_uint(f);
    return (u & 0x80000000u) ? ~u : (u | 0x80000000u);
}

__device__ __forceinline__ ushort_t f2b(float f) {   // RNE fp32->bf16
    unsigned u = __float_as_uint(f);
    return (ushort_t)((u + 0x7FFFu + ((u >> 16) & 1u)) >> 16);
}

__device__ __forceinline__ bf16x8 f2b8(float4 lo, float4 hi) {
    bf16x8 r;
    r[0] = (short)f2b(lo.x); r[1] = (short)f2b(lo.y);
    r[2] = (short)f2b(lo.z); r[3] = (short)f2b(lo.w);
    r[4] = (short)f2b(hi.x); r[5] = (short)f2b(hi.y);
    r[6] = (short)f2b(hi.z); r[7] = (short)f2b(hi.w);
    return r;
}

__device__ __forceinline__ void tile_decode(int t, int& ti, int& tj) {
    int a = 0, rem = t;
    while (rem >= NT - a) { rem -= NT - a; ++a; }
    ti = a; tj = a + rem;
}

__device__ __forceinline__ int rowbase(int i) {      // packed row start
    return i * N_SZ - (i * (i - 1)) / 2;
}

// -------- kAS: sym keys (LDS-resident) + radix select + bitmask + writes ----
// 1 block/batch, 1024 threads; blocks >= B_SZ do wkg prep (56 x 1024 = 57344).
// Phase 1: kA's 32x32 tile-pair loop, keys written straight into LDS kl.
// Phase 2/3: R16's proven radix select + tie rank + bitmask + coalesced writes.
__global__ __launch_bounds__(1024) void kAS(
    const float* __restrict__ gu, const float* __restrict__ nets,
    const int* __restrict__ net_index, const float* __restrict__ wg,
    ushort_t* __restrict__ wkg, float* __restrict__ out_base,
    ushort_t* __restrict__ adjb16)
{
    const int blk = blockIdx.x;
    const int tid = threadIdx.x;
    if (blk >= B_SZ) {
        // wkg prep: w -> bf16 kgroup layout (28 kgroups, 3 zero)
        int e = (blk - B_SZ) * 1024 + tid;     // 0..57343
        int kg = e >> 11;
        int rem = e & 2047;
        int n = rem >> 3;
        int ki = rem & 7;
        int k = kg * 8 + ki;
        wkg[e] = (k < FIN) ? f2b(wg[k * OUT_F + n]) : (ushort_t)0;
        return;
    }
    const int b = blk;

    __shared__ __align__(16) unsigned kl[NUPPER];   // 80.4 KB
    __shared__ float Hij[32][33];
    __shared__ float Hji[32][33];
    __shared__ unsigned hist[256];
    __shared__ unsigned sfx[256];
    __shared__ unsigned scanA[1024];
    __shared__ unsigned M[N_SZ][7];                 // full-square bitmask, 5.6 KB
    __shared__ unsigned sPrefix;
    __shared__ int sKK;

    const float* ub = gu + (size_t)b * NN;
    const float* lb = nets + (size_t)net_index[b] * NN;

    // ===== phase 1: keys -> LDS (28 tile-pairs; 1024 thr = one 32x32 tile) ===
    const int rr = tid >> 5;       // 0..31
    const int cc = tid & 31;       // 0..31
    for (int t = 0; t < NTILES; ++t) {
        int ti, tj; tile_decode(t, ti, tj);
        const int i0 = ti * 32, j0 = tj * 32;
        {
            int i = i0 + rr, j = j0 + cc;
            if (i < N_SZ && j < N_SZ) {
                float u = ub[i * N_SZ + j];
                u = fminf(fmaxf(u, 1e-10f), 1.0f - 1e-10f);
                Hij[rr][cc] = lb[i * N_SZ + j] - logf(-logf(u));
            }
            if (ti != tj) {
                int i2 = j0 + rr, j2 = i0 + cc;
                if (i2 < N_SZ && j2 < N_SZ) {
                    float u = ub[i2 * N_SZ + j2];
                    u = fminf(fmaxf(u, 1e-10f), 1.0f - 1e-10f);
                    Hji[rr][cc] = lb[i2 * N_SZ + j2] - logf(-logf(u));
                }
            }
        }
        __syncthreads();
        {
            int i = i0 + rr, j = j0 + cc;
            if (i < N_SZ && j < N_SZ && i <= j) {
                float hji = (ti == tj) ? Hij[cc][rr] : Hji[cc][rr];
                float sv = 0.5f * ((Hij[rr][cc]) + hji);
                kl[rowbase(i) + (j - i)] = sortkey(sv);
            }
        }
        __syncthreads();
    }
    for (int q = tid; q < N_SZ * 7; q += 1024) ((unsigned*)M)[q] = 0;

    // ===== phase 2: 4-round radix select (proven R16 code) ===================
    unsigned prefix = 0;
    int kk = KSEL;
    for (int round = 0; round < 4; ++round) {
        const int shift = 24 - 8 * round;
        if (tid < 256) hist[tid] = 0;
        __syncthreads();
        for (int idx = tid; idx < NUPPER; idx += 1024) {
            unsigned key = kl[idx];
            bool in = (round == 0) || ((key >> (shift + 8)) == prefix);
            if (in) atomicAdd(&hist[(key >> shift) & 255u], 1u);
        }
        __syncthreads();
        if (tid < 256) sfx[tid] = hist[tid];
        __syncthreads();
        #pragma unroll
        for (int off = 1; off < 256; off <<= 1) {
            unsigned add = 0;
            if (tid < 256 && tid + off < 256) add = sfx[tid + off];
            __syncthreads();
            if (tid < 256) sfx[tid] += add;
            __syncthreads();
        }
        if (tid < 256) {
            unsigned above = (tid < 255) ? sfx[tid + 1] : 0u;
            if (sfx[tid] >= (unsigned)kk && above < (unsigned)kk) {
                sPrefix = (prefix << 8) | (unsigned)tid;
                sKK = kk - (int)above;
            }
        }
        __syncthreads();
        prefix = sPrefix;
        kk = sKK;
        __syncthreads();
    }
    const unsigned kth = prefix;

    // ===== phase 3: tie rank -> bitmask -> coalesced writes ==================
    const int lo = tid * 20;
    const int hi = (lo + 20 < NUPPER) ? lo + 20 : NUPPER;
    unsigned mycnt = 0;
    for (int idx = lo; idx < hi; ++idx)
        if (kl[idx] == kth) ++mycnt;
    scanA[tid] = mycnt;
    __syncthreads();
    #pragma unroll
    for (int off = 1; off < 1024; off <<= 1) {
        unsigned add = (tid >= off) ? scanA[tid - off] : 0u;
        __syncthreads();
        scanA[tid] += add;
        __syncthreads();
    }
    unsigned rank = scanA[tid] - mycnt;   // exclusive prefix of tie counts

    if (lo < NUPPER) {
        int iLo = 0, iHi = N_SZ - 1;
        while (iLo < iHi) {
            int mid = (iLo + iHi + 1) >> 1;
            if (rowbase(mid) <= lo) iLo = mid; else iHi = mid - 1;
        }
        int i = iLo;
        int nextBase = rowbase(i + 1);
        for (int idx = lo; idx < hi; ++idx) {
            while (idx >= nextBase) { ++i; nextBase = rowbase(i + 1); }
            unsigned key = kl[idx];
            bool dec;
            if (key > kth) dec = true;
            else if (key == kth) { dec = (rank < (unsigned)kk); ++rank; }
            else dec = false;
            if (dec) {
                int j = i + (idx - rowbase(i));
                atomicOr(&M[i][j >> 5], 1u << (j & 31));
                atomicOr(&M[j][i >> 5], 1u << (i & 31));
            }
        }
    }
    __syncthreads();

    float* adj = out_base + ADJ_OFF + (size_t)b * NN;
    for (int e = tid; e < 10000; e += 1024) {         // 10000 float4 = 40000
        int i = e / 50;
        int j0 = (e % 50) * 4;
        unsigned wbits = M[i][j0 >> 5] >> (j0 & 31);
        float4 v;
        v.x = (wbits & 1u) ? 1.0f : 0.0f;
        v.y = (wbits & 2u) ? 1.0f : 0.0f;
        v.z = (wbits & 4u) ? 1.0f : 0.0f;
        v.w = (wbits & 8u) ? 1.0f : 0.0f;
        *(float4*)(adj + (size_t)i * N_SZ + j0) = v;
    }
    ushort_t* ab = adjb16 + (size_t)b * (N_SZ * ADJ_STRIDE);
    for (int e = tid; e < 5600; e += 1024) {          // 5600 u16x8 = 44800
        int i = e / 28;
        int j0 = (e % 28) * 8;
        unsigned wbits = (j0 < N_SZ) ? (M[i][j0 >> 5] >> (j0 & 31)) : 0u;
        u16x8 v;
        #pragma unroll
        for (int q = 0; q < 8; ++q) {
            int j = j0 + q;
            v[q] = (j < N_SZ && (wbits & (1u << q))) ? (ushort_t)0x3F80 : (ushort_t)0;
        }
        *(u16x8*)(ab + (size_t)i * ADJ_STRIDE + j0) = v;
    }
}

// -------- K2: XW = x @ w_gnn via bf16 MFMA, barrier-free main loop ----------
__global__ __launch_bounds__(256) void k2_mfma(
    const float* __restrict__ x, const ushort_t* __restrict__ wkg,
    ushort_t* __restrict__ xwm)
{
    const int r0 = blockIdx.x * 64;
    const int tid = threadIdx.x;
    const int w = tid >> 6;
    const int l = tid & 63;
    const int g = l >> 4;
    const int r = l & 15;

    __shared__ __align__(16) ushort_t Cs[64 * 256];   // 32 KB epilogue buffer

    f32x4 acc[4][4];
    #pragma unroll
    for (int mf = 0; mf < 4; ++mf)
        #pragma unroll
        for (int nf = 0; nf < 4; ++nf)
            acc[mf][nf] = (f32x4){0.f, 0.f, 0.f, 0.f};

    for (int c = 0; c < 7; ++c) {
        // k>=200 (chunk 6, g>0): clamp addr; B kgroups 25..27 are zero.
        const int koff = (c * 32 + g * 8 < FIN) ? (c * 32 + g * 8) : 0;
        bf16x8 af[4], bf[4];
        #pragma unroll
        for (int mf = 0; mf < 4; ++mf) {
            const float* ap = x + (size_t)(r0 + mf * 16 + r) * FIN + koff;
            float4 lo = *(const float4*)ap;
            float4 hi = *(const float4*)(ap + 4);
            af[mf] = f2b8(lo, hi);
        }
        #pragma unroll
        for (int nf = 0; nf < 4; ++nf)
            bf[nf] = *(const bf16x8*)(wkg + c * 8192 + g * 2048 + (w * 64 + nf * 16 + r) * 8);
        #pragma unroll
        for (int mf = 0; mf < 4; ++mf)
            #pragma unroll
            for (int nf = 0; nf < 4; ++nf)
                acc[mf][nf] = __builtin_amdgcn_mfma_f32_16x16x32_bf16(
                    af[mf], bf[nf], acc[mf][nf], 0, 0, 0);
    }

    // scatter to Cs in kgroup layout (local rows 0..63)
    #pragma unroll
    for (int mf = 0; mf < 4; ++mf) {
        #pragma unroll
        for (int jj = 0; jj < 4; ++jj) {
            int row = mf * 16 + g * 4 + jj;
            #pragma unroll
            for (int nf = 0; nf < 4; ++nf) {
                int col = w * 64 + nf * 16 + r;
                Cs[((row >> 3) << 11) + col * 8 + (row & 7)] = f2b(acc[mf][nf][jj]);
            }
        }
    }
    __syncthreads();
    // linear write-out: 8 local kgroups (8-row groups never cross batch bound)
    #pragma unroll
    for (int kg = 0; kg < 8; ++kg) {
        int grow0 = r0 + kg * 8;
        int bb = grow0 / N_SZ;
        int jb = grow0 % N_SZ;
        ushort_t* dst = xwm + (size_t)bb * XWM_PB + ((jb >> 3) << 11);
        *(int4*)(dst + tid * 8) = *(const int4*)(Cs + (kg << 11) + tid * 8);
    }
}

// -------- K3 fused v5: 16-row tiles (3328 blocks), A-prefetch, k4 folded ----
// XCD-bijective: all 13 tiles of a batch land on one XCD.
__global__ __launch_bounds__(256) void k3_fused(
    const ushort_t* __restrict__ adjb16, const ushort_t* __restrict__ xwm,
    const float* __restrict__ wl, const float* __restrict__ bl,
    float* __restrict__ out_base)
{
    const int blk = blockIdx.x;
    const int xcd = blk & 7;
    const int idx = blk >> 3;            // 0..415
    const int b = xcd + 8 * (idx / 13);
    const int mt = idx % 13;             // 13 tiles x 16 rows = 208 (>=200 clamp)
    const int tid = threadIdx.x;
    const int w = tid >> 6;
    const int l = tid & 63;
    const int g = l >> 4;
    const int r = l & 15;

    const ushort_t* adjb = adjb16 + (size_t)b * (N_SZ * ADJ_STRIDE);
    const ushort_t* xwb = xwm + (size_t)b * XWM_PB;

    __shared__ __align__(16) float Es[16 * 256];      // 16 KB; red aliases later
    float (*red)[4][4][8] = (float(*)[4][4][8])Es;    // [w][g][jslot][cls]

    // prefetch all 7 A fragments (28 VGPR)
    int arow = mt * 16 + r; if (arow > N_SZ - 1) arow = N_SZ - 1;
    bf16x8 aa[7];
    #pragma unroll
    for (int c = 0; c < 7; ++c)
        aa[c] = *(const bf16x8*)(adjb + arow * ADJ_STRIDE + c * 32 + g * 8);

    f32x4 acc[4];
    #pragma unroll
    for (int nf = 0; nf < 4; ++nf) acc[nf] = (f32x4){0.f, 0.f, 0.f, 0.f};

    #pragma unroll
    for (int c = 0; c < 7; ++c) {
        bf16x8 bf[4];
        // chunk 6, g>0 reads kgroups 25..27 (next batch / wkg: finite);
        // A is zero there (adjb16 K-padding) so product vanishes.
        #pragma unroll
        for (int nf = 0; nf < 4; ++nf)
            bf[nf] = *(const bf16x8*)(xwb + c * 8192 + g * 2048 + (w * 64 + nf * 16 + r) * 8);
        #pragma unroll
        for (int nf = 0; nf < 4; ++nf)
            acc[nf] = __builtin_amdgcn_mfma_f32_16x16x32_bf16(
                aa[c], bf[nf], acc[nf], 0, 0, 0);
    }

    // ---- phase A: emb -> Es (relu), then coalesced float4 stores ----
    #pragma unroll
    for (int j = 0; j < 4; ++j) {
        int rowl = g * 4 + j;
        #pragma unroll
        for (int nf = 0; nf < 4; ++nf)
            Es[rowl * 256 + w * 64 + nf * 16 + r] = fmaxf(acc[nf][j], 0.0f);
    }
    __syncthreads();
    #pragma unroll
    for (int q = 0; q < 4; ++q) {
        int e = q * 256 + tid;
        int rowl = e >> 6;               // 64 float4 per row
        int c4 = e & 63;
        int grow = mt * 16 + rowl;
        if (grow < N_SZ) {
            float4 v = *(const float4*)(Es + rowl * 256 + c4 * 4);
            *(float4*)(out_base + EMB_OFF + ((size_t)b * N_SZ + grow) * OUT_F + c4 * 4) = v;
        }
    }
    __syncthreads();   // all Es reads done before red overwrites it

    // ---- phase B: out = emb @ w_lin + b (from acc regs) ----
    float wlv[4][NCLS];
    #pragma unroll
    for (int nf = 0; nf < 4; ++nf) {
        int col = w * 64 + nf * 16 + r;
        #pragma unroll
        for (int cls = 0; cls < NCLS; ++cls) wlv[nf][cls] = wl[col * NCLS + cls];
    }
    #pragma unroll
    for (int j = 0; j < 4; ++j) {
        float e0 = fmaxf(acc[0][j], 0.0f);
        float e1 = fmaxf(acc[1][j], 0.0f);
        float e2 = fmaxf(acc[2][j], 0.0f);
        float e3 = fmaxf(acc[3][j], 0.0f);
        float pr[NCLS];
        #pragma unroll
        for (int cls = 0; cls < NCLS; ++cls)
            pr[cls] = e0 * wlv[0][cls] + e1 * wlv[1][cls]
                    + e2 * wlv[2][cls] + e3 * wlv[3][cls];
        #pragma unroll
        for (int off = 1; off <= 8; off <<= 1) {
            #pragma unroll
            for (int cls = 0; cls < NCLS; ++cls)
                pr[cls] += __shfl_xor(pr[cls], off, 64);
        }
        if (r < NCLS) red[w][g][j][r] = pr[r];
    }
    __syncthreads();

    // final combine over waves: 128 outputs (16 rows x 8 cls)
    if (tid < 16 * NCLS) {
        int rowl = tid >> 3, cls = tid & 7;
        int gg = rowl >> 2, jj = rowl & 3;
        int grow = mt * 16 + rowl;
        if (grow < N_SZ) {
            float s = red[0][gg][jj][cls] + red[1][gg][jj][cls]
                    + red[2][gg][jj][cls] + red[3][gg][jj][cls] + bl[cls];
            out_base[((size_t)b * N_SZ + grow) * NCLS + cls] = s;
        }
    }
}

extern "C" void kernel_launch(void* const* d_in, const int* in_sizes, int n_in,
                              void* d_out, int out_size, void* d_ws, size_t ws_size,
                              hipStream_t stream) {
    const float* x    = (const float*)d_in[0];
    const float* gu   = (const float*)d_in[1];
    const float* nets = (const float*)d_in[2];
    const float* wg   = (const float*)d_in[3];
    const float* wl   = (const float*)d_in[4];
    const float* bl   = (const float*)d_in[5];
    const int*   nidx = (const int*)d_in[6];
    float* out = (float*)d_out;

    char* ws = (char*)d_ws;
    ushort_t* xwm     = (ushort_t*)ws;                  // offset 0; k2 after kAS
    ushort_t* wkg     = (ushort_t*)(ws + WKG_OFF_B);
    ushort_t* adjb16  = (ushort_t*)(ws + ADJB16_OFF_B);

    kAS<<<B_SZ + 56, 1024, 0, stream>>>(gu, nets, nidx, wg, wkg, out, adjb16);
    k2_mfma<<<(B_SZ * N_SZ) / 64, 256, 0, stream>>>(x, wkg, xwm);
    k3_fused<<<B_SZ * 13, 256, 0, stream>>>(adjb16, xwm, wl, bl, out);
}

// Round 19
// 135.160 us; speedup vs baseline: 1.0637x; 1.0637x over previous
//
#include <hip/hip_runtime.h>
#include <math.h>

#define B_SZ 256
#define N_SZ 200
#define NN (N_SZ * N_SZ)          // 40000
#define FIN 200
#define OUT_F 256
#define NCLS 8
#define KSEL 3980
#define NUPPER 20100              // N*(N+1)/2
#define KSTRIDE 20128
#define NT 7                      // ceil(200/32) tiles per dim
#define NTILES 28                 // NT*(NT+1)/2 upper tile pairs

#define ADJ_STRIDE 224            // adj_bf16 row stride (K-padded zeros beyond 199)
#define KGRP_PB 25                // kgroups per batch (200/8)
#define XWM_PB (KGRP_PB * 2048)   // 51200 elems per batch in mfma layout

#define EMB_OFF (B_SZ * N_SZ * NCLS)               // 409600
#define ADJ_OFF (EMB_OFF + B_SZ * N_SZ * OUT_F)    // 13516800

// ---- ws layout (bytes) ----
// keys:    [0, 20,611,072)        written kA, read kSelW; dead after kSelW
// XW_mfma: [0, 26,214,400)        aliases keys; written k2 (after kSelW), read k3
// w_kgrp:  [26,214,400, +114,688) bf16 w kgroup layout, 28 kgrp (3 zero)
// adjb16:  [26,329,088, +22,937,600) end 49,266,688
#define KEYS_OFF_B   0
#define WKG_OFF_B    26214400
#define ADJB16_OFF_B 26329088

typedef unsigned short ushort_t;
typedef float f32x4 __attribute__((ext_vector_type(4)));
typedef short bf16x8 __attribute__((ext_vector_type(8)));
typedef ushort_t u16x8 __attribute__((ext_vector_type(8)));

__device__ __forceinline__ unsigned sortkey(float f) {
    unsigned u = __float_as_uint(f);
    return (u & 0x80000000u) ? ~u : (u | 0x80000000u);
}

__device__ __forceinline__ ushort_t f2b(float f) {   // RNE fp32->bf16
    unsigned u = __float_as_uint(f);
    return (ushort_t)((u + 0x7FFFu + ((u >> 16) & 1u)) >> 16);
}

__device__ __forceinline__ bf16x8 f2b8(float4 lo, float4 hi) {
    bf16x8 r;
    r[0] = (short)f2b(lo.x); r[1] = (short)f2b(lo.y);
    r[2] = (short)f2b(lo.z); r[3] = (short)f2b(lo.w);
    r[4] = (short)f2b(hi.x); r[5] = (short)f2b(hi.y);
    r[6] = (short)f2b(hi.z); r[7] = (short)f2b(hi.w);
    return r;
}

__device__ __forceinline__ void tile_decode(int t, int& ti, int& tj) {
    int a = 0, rem = t;
    while (rem >= NT - a) { rem -= NT - a; ++a; }
    ti = a; tj = a + rem;
}

__device__ __forceinline__ int rowbase(int i) {      // packed row start
    return i * N_SZ - (i * (i - 1)) / 2;
}

// -------- kA: sym keys (packed upper-tri) + fused kWprep tail blocks --------
__global__ __launch_bounds__(256) void kA(
    const float* __restrict__ gu, const float* __restrict__ nets,
    const int* __restrict__ net_index, unsigned* __restrict__ keys,
    const float* __restrict__ wg, ushort_t* __restrict__ wkg)
{
    const int blk = blockIdx.x;
    if (blk >= B_SZ * NTILES) {
        int pb = blk - B_SZ * NTILES;    // 0..223
        int e = pb * 256 + threadIdx.x;
        int kg = e >> 11;
        int rem = e & 2047;
        int n = rem >> 3;
        int ki = rem & 7;
        int k = kg * 8 + ki;
        wkg[e] = (k < FIN) ? f2b(wg[k * OUT_F + n]) : (ushort_t)0;
        return;
    }
    const int b = blk / NTILES;
    int ti, tj; tile_decode(blk % NTILES, ti, tj);
    const int i0 = ti * 32, j0 = tj * 32;
    const float* ub = gu + (size_t)b * NN;
    const float* lb = nets + (size_t)net_index[b] * NN;

    __shared__ float Hij[32][33];
    __shared__ float Hji[32][33];

    const int r = threadIdx.x >> 5;
    const int c = threadIdx.x & 31;

    #pragma unroll
    for (int s = 0; s < 4; ++s) {
        int rr = r + 8 * s;
        int i = i0 + rr, j = j0 + c;
        if (i < N_SZ && j < N_SZ) {
            float u = ub[i * N_SZ + j];
            u = fminf(fmaxf(u, 1e-10f), 1.0f - 1e-10f);
            Hij[rr][c] = lb[i * N_SZ + j] - logf(-logf(u));
        }
        if (ti != tj) {
            int i2 = j0 + rr, j2 = i0 + c;
            if (i2 < N_SZ && j2 < N_SZ) {
                float u = ub[i2 * N_SZ + j2];
                u = fminf(fmaxf(u, 1e-10f), 1.0f - 1e-10f);
                Hji[rr][c] = lb[i2 * N_SZ + j2] - logf(-logf(u));
            }
        }
    }
    __syncthreads();

    unsigned* kb = keys + (size_t)b * KSTRIDE;
    #pragma unroll
    for (int s = 0; s < 4; ++s) {
        int rr = r + 8 * s;
        int i = i0 + rr, j = j0 + c;
        if (i < N_SZ && j < N_SZ && i <= j) {
            float hji = (ti == tj) ? Hij[c][rr] : Hji[c][rr];
            float sv = 0.5f * ((Hij[rr][c]) + hji);
            int base = i * N_SZ - (i * (i - 1)) / 2;
            kb[base + (j - i)] = sortkey(sv);
        }
    }
}

// -------- kSelW v4: radix select (shfl scans) + bitmask + coalesced writes --
// 1024 threads, 1 block/batch. ~19 barriers total (was ~90 in v3).
__global__ __launch_bounds__(1024) void kSelW(
    const unsigned* __restrict__ keys, float* __restrict__ out_base,
    ushort_t* __restrict__ adjb16)
{
    const int b = blockIdx.x;
    const int tid = threadIdx.x;
    const int lane = tid & 63;
    const int wv = tid >> 6;                        // 0..15
    __shared__ __align__(16) unsigned kl[NUPPER];   // 80.4 KB
    __shared__ unsigned hist[256];
    __shared__ unsigned wtot[16];
    __shared__ unsigned M[N_SZ][7];                 // full-square bitmask, 5.6 KB
    __shared__ unsigned sPrefix;
    __shared__ int sKK;

    // load keys (int4-vectorized; 20100 = 4*5025)
    {
        const int4* kb4 = (const int4*)(keys + (size_t)b * KSTRIDE);
        int4* kl4 = (int4*)kl;
        for (int q = tid; q < 5025; q += 1024) kl4[q] = kb4[q];
    }
    for (int q = tid; q < N_SZ * 7; q += 1024) ((unsigned*)M)[q] = 0;

    unsigned prefix = 0;
    int kk = KSEL;
    for (int round = 0; round < 4; ++round) {
        const int shift = 24 - 8 * round;
        if (tid < 256) hist[tid] = 0;
        __syncthreads();                            // also covers kl loads (round 0)
        for (int idx = tid; idx < NUPPER; idx += 1024) {
            unsigned key = kl[idx];
            bool in = (round == 0) || ((key >> (shift + 8)) == prefix);
            if (in) atomicAdd(&hist[(key >> shift) & 255u], 1u);
        }
        __syncthreads();
        // suffix scan of hist via shfl within waves 0..3 (tid<256)
        unsigned own = 0, v = 0;
        if (tid < 256) {
            own = hist[tid];
            v = own;
            #pragma unroll
            for (int off = 1; off < 64; off <<= 1) {
                unsigned t = __shfl_down(v, off, 64);
                if (lane + off < 64) v += t;
            }
            if (lane == 0) wtot[wv] = v;            // whole-wave sum at lane 0
        }
        __syncthreads();
        if (tid < 256) {
            unsigned add = 0;
            #pragma unroll
            for (int q = 1; q < 4; ++q) if (wv + q < 4) add += wtot[wv + q];
            unsigned sfxv = v + add;                // sum_{u>=tid} hist[u]
            unsigned above = sfxv - own;            // sum_{u>tid}
            if (sfxv >= (unsigned)kk && above < (unsigned)kk) {
                sPrefix = (prefix << 8) | (unsigned)tid;
                sKK = kk - (int)above;
            }
        }
        __syncthreads();
        prefix = sPrefix;
        kk = sKK;
    }
    const unsigned kth = prefix;

    // tie ranking: blocked contiguous ranges (ascending packed == flat order)
    const int lo = tid * 20;
    const int hi = (lo + 20 < NUPPER) ? lo + 20 : NUPPER;
    unsigned mycnt = 0;
    for (int idx = lo; idx < hi; ++idx)
        if (kl[idx] == kth) ++mycnt;
    // inclusive prefix scan via shfl_up + wave-total combine (1 barrier)
    unsigned v = mycnt;
    #pragma unroll
    for (int off = 1; off < 64; off <<= 1) {
        unsigned t = __shfl_up(v, off, 64);
        if (lane >= off) v += t;
    }
    if (lane == 63) wtot[wv] = v;
    __syncthreads();
    unsigned addp = 0;
    for (int q = 0; q < wv; ++q) addp += wtot[q];
    unsigned rank = v + addp - mycnt;               // exclusive prefix

    // decision pass -> bitmask (both triangles)
    if (lo < NUPPER) {
        int iLo = 0, iHi = N_SZ - 1;
        while (iLo < iHi) {
            int mid = (iLo + iHi + 1) >> 1;
            if (rowbase(mid) <= lo) iLo = mid; else iHi = mid - 1;
        }
        int i = iLo;
        int nextBase = rowbase(i + 1);
        for (int idx = lo; idx < hi; ++idx) {
            while (idx >= nextBase) { ++i; nextBase = rowbase(i + 1); }
            unsigned key = kl[idx];
            bool dec;
            if (key > kth) dec = true;
            else if (key == kth) { dec = (rank < (unsigned)kk); ++rank; }
            else dec = false;
            if (dec) {
                int j = i + (idx - rowbase(i));
                atomicOr(&M[i][j >> 5], 1u << (j & 31));
                atomicOr(&M[j][i >> 5], 1u << (i & 31));
            }
        }
    }
    __syncthreads();

    // write fp32 adj -- row-major float4, one broadcast word read per 4 elems
    float* adj = out_base + ADJ_OFF + (size_t)b * NN;
    for (int e = tid; e < 10000; e += 1024) {         // 10000 float4 = 40000
        int i = e / 50;
        int j0 = (e % 50) * 4;
        unsigned wbits = M[i][j0 >> 5] >> (j0 & 31);
        float4 v4;
        v4.x = (wbits & 1u) ? 1.0f : 0.0f;
        v4.y = (wbits & 2u) ? 1.0f : 0.0f;
        v4.z = (wbits & 4u) ? 1.0f : 0.0f;
        v4.w = (wbits & 8u) ? 1.0f : 0.0f;
        *(float4*)(adj + (size_t)i * N_SZ + j0) = v4;
    }
    // write adjb16 (K-padded 224) -- ushort8, one word read per 8 elems
    ushort_t* ab = adjb16 + (size_t)b * (N_SZ * ADJ_STRIDE);
    for (int e = tid; e < 5600; e += 1024) {          // 5600 u16x8 = 44800
        int i = e / 28;
        int j0 = (e % 28) * 8;
        unsigned wbits = (j0 < N_SZ) ? (M[i][j0 >> 5] >> (j0 & 31)) : 0u;
        u16x8 v8;
        #pragma unroll
        for (int q = 0; q < 8; ++q) {
            int j = j0 + q;
            v8[q] = (j < N_SZ && (wbits & (1u << q))) ? (ushort_t)0x3F80 : (ushort_t)0;
        }
        *(u16x8*)(ab + (size_t)i * ADJ_STRIDE + j0) = v8;
    }
}

// -------- K2: XW = x @ w_gnn via bf16 MFMA, barrier-free main loop ----------
__global__ __launch_bounds__(256) void k2_mfma(
    const float* __restrict__ x, const ushort_t* __restrict__ wkg,
    ushort_t* __restrict__ xwm)
{
    const int r0 = blockIdx.x * 64;
    const int tid = threadIdx.x;
    const int w = tid >> 6;
    const int l = tid & 63;
    const int g = l >> 4;
    const int r = l & 15;

    __shared__ __align__(16) ushort_t Cs[64 * 256];   // 32 KB epilogue buffer

    f32x4 acc[4][4];
    #pragma unroll
    for (int mf = 0; mf < 4; ++mf)
        #pragma unroll
        for (int nf = 0; nf < 4; ++nf)
            acc[mf][nf] = (f32x4){0.f, 0.f, 0.f, 0.f};

    for (int c = 0; c < 7; ++c) {
        // k>=200 (chunk 6, g>0): clamp addr; B kgroups 25..27 are zero.
        const int koff = (c * 32 + g * 8 < FIN) ? (c * 32 + g * 8) : 0;
        bf16x8 af[4], bf[4];
        #pragma unroll
        for (int mf = 0; mf < 4; ++mf) {
            const float* ap = x + (size_t)(r0 + mf * 16 + r) * FIN + koff;
            float4 lo = *(const float4*)ap;
            float4 hi = *(const float4*)(ap + 4);
            af[mf] = f2b8(lo, hi);
        }
        #pragma unroll
        for (int nf = 0; nf < 4; ++nf)
            bf[nf] = *(const bf16x8*)(wkg + c * 8192 + g * 2048 + (w * 64 + nf * 16 + r) * 8);
        #pragma unroll
        for (int mf = 0; mf < 4; ++mf)
            #pragma unroll
            for (int nf = 0; nf < 4; ++nf)
                acc[mf][nf] = __builtin_amdgcn_mfma_f32_16x16x32_bf16(
                    af[mf], bf[nf], acc[mf][nf], 0, 0, 0);
    }

    // scatter to Cs in kgroup layout (local rows 0..63)
    #pragma unroll
    for (int mf = 0; mf < 4; ++mf) {
        #pragma unroll
        for (int jj = 0; jj < 4; ++jj) {
            int row = mf * 16 + g * 4 + jj;
            #pragma unroll
            for (int nf = 0; nf < 4; ++nf) {
                int col = w * 64 + nf * 16 + r;
                Cs[((row >> 3) << 11) + col * 8 + (row & 7)] = f2b(acc[mf][nf][jj]);
            }
        }
    }
    __syncthreads();
    // linear write-out: 8 local kgroups (8-row groups never cross batch bound)
    #pragma unroll
    for (int kg = 0; kg < 8; ++kg) {
        int grow0 = r0 + kg * 8;
        int bb = grow0 / N_SZ;
        int jb = grow0 % N_SZ;
        ushort_t* dst = xwm + (size_t)bb * XWM_PB + ((jb >> 3) << 11);
        *(int4*)(dst + tid * 8) = *(const int4*)(Cs + (kg << 11) + tid * 8);
    }
}

// -------- K3 fused v5: 16-row tiles (3328 blocks), A-prefetch, k4 folded ----
// XCD-bijective: all 13 tiles of a batch land on one XCD.
__global__ __launch_bounds__(256) void k3_fused(
    const ushort_t* __restrict__ adjb16, const ushort_t* __restrict__ xwm,
    const float* __restrict__ wl, const float* __restrict__ bl,
    float* __restrict__ out_base)
{
    const int blk = blockIdx.x;
    const int xcd = blk & 7;
    const int idx = blk >> 3;            // 0..415
    const int b = xcd + 8 * (idx / 13);
    const int mt = idx % 13;             // 13 tiles x 16 rows = 208 (>=200 clamp)
    const int tid = threadIdx.x;
    const int w = tid >> 6;
    const int l = tid & 63;
    const int g = l >> 4;
    const int r = l & 15;

    const ushort_t* adjb = adjb16 + (size_t)b * (N_SZ * ADJ_STRIDE);
    const ushort_t* xwb = xwm + (size_t)b * XWM_PB;

    __shared__ __align__(16) float Es[16 * 256];      // 16 KB; red aliases later
    float (*red)[4][4][8] = (float(*)[4][4][8])Es;    // [w][g][jslot][cls]

    // prefetch all 7 A fragments (28 VGPR)
    int arow = mt * 16 + r; if (arow > N_SZ - 1) arow = N_SZ - 1;
    bf16x8 aa[7];
    #pragma unroll
    for (int c = 0; c < 7; ++c)
        aa[c] = *(const bf16x8*)(adjb + arow * ADJ_STRIDE + c * 32 + g * 8);

    f32x4 acc[4];
    #pragma unroll
    for (int nf = 0; nf < 4; ++nf) acc[nf] = (f32x4){0.f, 0.f, 0.f, 0.f};

    #pragma unroll
    for (int c = 0; c < 7; ++c) {
        bf16x8 bf[4];
        // chunk 6, g>0 reads kgroups 25..27 (next batch / wkg: finite);
        // A is zero there (adjb16 K-padding) so product vanishes.
        #pragma unroll
        for (int nf = 0; nf < 4; ++nf)
            bf[nf] = *(const bf16x8*)(xwb + c * 8192 + g * 2048 + (w * 64 + nf * 16 + r) * 8);
        #pragma unroll
        for (int nf = 0; nf < 4; ++nf)
            acc[nf] = __builtin_amdgcn_mfma_f32_16x16x32_bf16(
                aa[c], bf[nf], acc[nf], 0, 0, 0);
    }

    // ---- phase A: emb -> Es (relu), then coalesced float4 stores ----
    #pragma unroll
    for (int j = 0; j < 4; ++j) {
        int rowl = g * 4 + j;
        #pragma unroll
        for (int nf = 0; nf < 4; ++nf)
            Es[rowl * 256 + w * 64 + nf * 16 + r] = fmaxf(acc[nf][j], 0.0f);
    }
    __syncthreads();
    #pragma unroll
    for (int q = 0; q < 4; ++q) {
        int e = q * 256 + tid;
        int rowl = e >> 6;               // 64 float4 per row
        int c4 = e & 63;
        int grow = mt * 16 + rowl;
        if (grow < N_SZ) {
            float4 v = *(const float4*)(Es + rowl * 256 + c4 * 4);
            *(float4*)(out_base + EMB_OFF + ((size_t)b * N_SZ + grow) * OUT_F + c4 * 4) = v;
        }
    }
    __syncthreads();   // all Es reads done before red overwrites it

    // ---- phase B: out = emb @ w_lin + b (from acc regs) ----
    float wlv[4][NCLS];
    #pragma unroll
    for (int nf = 0; nf < 4; ++nf) {
        int col = w * 64 + nf * 16 + r;
        #pragma unroll
        for (int cls = 0; cls < NCLS; ++cls) wlv[nf][cls] = wl[col * NCLS + cls];
    }
    #pragma unroll
    for (int j = 0; j < 4; ++j) {
        float e0 = fmaxf(acc[0][j], 0.0f);
        float e1 = fmaxf(acc[1][j], 0.0f);
        float e2 = fmaxf(acc[2][j], 0.0f);
        float e3 = fmaxf(acc[3][j], 0.0f);
        float pr[NCLS];
        #pragma unroll
        for (int cls = 0; cls < NCLS; ++cls)
            pr[cls] = e0 * wlv[0][cls] + e1 * wlv[1][cls]
                    + e2 * wlv[2][cls] + e3 * wlv[3][cls];
        #pragma unroll
        for (int off = 1; off <= 8; off <<= 1) {
            #pragma unroll
            for (int cls = 0; cls < NCLS; ++cls)
                pr[cls] += __shfl_xor(pr[cls], off, 64);
        }
        if (r < NCLS) red[w][g][j][r] = pr[r];
    }
    __syncthreads();

    // final combine over waves: 128 outputs (16 rows x 8 cls)
    if (tid < 16 * NCLS) {
        int rowl = tid >> 3, cls = tid & 7;
        int gg = rowl >> 2, jj = rowl & 3;
        int grow = mt * 16 + rowl;
        if (grow < N_SZ) {
            float s = red[0][gg][jj][cls] + red[1][gg][jj][cls]
                    + red[2][gg][jj][cls] + red[3][gg][jj][cls] + bl[cls];
            out_base[((size_t)b * N_SZ + grow) * NCLS + cls] = s;
        }
    }
}

extern "C" void kernel_launch(void* const* d_in, const int* in_sizes, int n_in,
                              void* d_out, int out_size, void* d_ws, size_t ws_size,
                              hipStream_t stream) {
    const float* x    = (const float*)d_in[0];
    const float* gu   = (const float*)d_in[1];
    const float* nets = (const float*)d_in[2];
    const float* wg   = (const float*)d_in[3];
    const float* wl   = (const float*)d_in[4];
    const float* bl   = (const float*)d_in[5];
    const int*   nidx = (const int*)d_in[6];
    float* out = (float*)d_out;

    char* ws = (char*)d_ws;
    unsigned* keys    = (unsigned*)(ws + KEYS_OFF_B);
    ushort_t* xwm     = (ushort_t*)(ws + KEYS_OFF_B);   // aliases keys; k2 after kSelW
    ushort_t* wkg     = (ushort_t*)(ws + WKG_OFF_B);
    ushort_t* adjb16  = (ushort_t*)(ws + ADJB16_OFF_B);

    kA<<<B_SZ * NTILES + 224, 256, 0, stream>>>(gu, nets, nidx, keys, wg, wkg);
    kSelW<<<B_SZ, 1024, 0, stream>>>(keys, out, adjb16);
    k2_mfma<<<(B_SZ * N_SZ) / 64, 256, 0, stream>>>(x, wkg, xwm);
    k3_fused<<<B_SZ * 13, 256, 0, stream>>>(adjb16, xwm, wl, bl, out);
}

// Round 20
// 126.818 us; speedup vs baseline: 1.1337x; 1.0658x over previous
//
#include <hip/hip_runtime.h>
#include <math.h>

#define B_SZ 256
#define N_SZ 200
#define NN (N_SZ * N_SZ)          // 40000
#define FIN 200
#define OUT_F 256
#define NCLS 8
#define KSEL 3980
#define NUPPER 20100              // N*(N+1)/2
#define KSTRIDE 20128
#define NT 7                      // ceil(200/32) tiles per dim
#define NTILES 28                 // NT*(NT+1)/2 upper tile pairs

#define KGRP_PB 25                // kgroups per batch (200/8)
#define XWM_PB (KGRP_PB * 2048)   // 51200 elems per batch in mfma layout
#define MROW_W 8                  // words per mask row (7 real + 1 pad)
#define MG_PB (N_SZ * MROW_W)     // 1600 words per batch

#define EMB_OFF (B_SZ * N_SZ * NCLS)               // 409600
#define ADJ_OFF (EMB_OFF + B_SZ * N_SZ * OUT_F)    // 13516800

// ---- ws layout (bytes) ----
// keys:    [0, 20,611,072)        written kA, read kSelW; dead after kSelW
// XW_mfma: [0, 26,214,400)        aliases keys; written k2 (after kSelW), read k3
// w_kgrp:  [26,214,400, +114,688) bf16 w kgroup layout, 28 kgrp (3 zero)
// Mg:      [26,329,088, +1,638,400) adjacency bitmask [B][200][8] words
#define KEYS_OFF_B   0
#define WKG_OFF_B    26214400
#define MG_OFF_B     26329088

typedef unsigned short ushort_t;
typedef float f32x4 __attribute__((ext_vector_type(4)));
typedef short bf16x8 __attribute__((ext_vector_type(8)));

__device__ __forceinline__ unsigned sortkey(float f) {
    unsigned u = __float_as_uint(f);
    return (u & 0x80000000u) ? ~u : (u | 0x80000000u);
}

__device__ __forceinline__ ushort_t f2b(float f) {   // RNE fp32->bf16
    unsigned u = __float_as_uint(f);
    return (ushort_t)((u + 0x7FFFu + ((u >> 16) & 1u)) >> 16);
}

__device__ __forceinline__ bf16x8 f2b8(float4 lo, float4 hi) {
    bf16x8 r;
    r[0] = (short)f2b(lo.x); r[1] = (short)f2b(lo.y);
    r[2] = (short)f2b(lo.z); r[3] = (short)f2b(lo.w);
    r[4] = (short)f2b(hi.x); r[5] = (short)f2b(hi.y);
    r[6] = (short)f2b(hi.z); r[7] = (short)f2b(hi.w);
    return r;
}

__device__ __forceinline__ void tile_decode(int t, int& ti, int& tj) {
    int a = 0, rem = t;
    while (rem >= NT - a) { rem -= NT - a; ++a; }
    ti = a; tj = a + rem;
}

__device__ __forceinline__ int rowbase(int i) {      // packed row start
    return i * N_SZ - (i * (i - 1)) / 2;
}

// -------- kA: sym keys (packed upper-tri) + fused kWprep tail blocks --------
__global__ __launch_bounds__(256) void kA(
    const float* __restrict__ gu, const float* __restrict__ nets,
    const int* __restrict__ net_index, unsigned* __restrict__ keys,
    const float* __restrict__ wg, ushort_t* __restrict__ wkg)
{
    const int blk = blockIdx.x;
    if (blk >= B_SZ * NTILES) {
        int pb = blk - B_SZ * NTILES;    // 0..223
        int e = pb * 256 + threadIdx.x;
        int kg = e >> 11;
        int rem = e & 2047;
        int n = rem >> 3;
        int ki = rem & 7;
        int k = kg * 8 + ki;
        wkg[e] = (k < FIN) ? f2b(wg[k * OUT_F + n]) : (ushort_t)0;
        return;
    }
    const int b = blk / NTILES;
    int ti, tj; tile_decode(blk % NTILES, ti, tj);
    const int i0 = ti * 32, j0 = tj * 32;
    const float* ub = gu + (size_t)b * NN;
    const float* lb = nets + (size_t)net_index[b] * NN;

    __shared__ float Hij[32][33];
    __shared__ float Hji[32][33];

    const int r = threadIdx.x >> 5;
    const int c = threadIdx.x & 31;

    #pragma unroll
    for (int s = 0; s < 4; ++s) {
        int rr = r + 8 * s;
        int i = i0 + rr, j = j0 + c;
        if (i < N_SZ && j < N_SZ) {
            float u = ub[i * N_SZ + j];
            u = fminf(fmaxf(u, 1e-10f), 1.0f - 1e-10f);
            Hij[rr][c] = lb[i * N_SZ + j] - logf(-logf(u));
        }
        if (ti != tj) {
            int i2 = j0 + rr, j2 = i0 + c;
            if (i2 < N_SZ && j2 < N_SZ) {
                float u = ub[i2 * N_SZ + j2];
                u = fminf(fmaxf(u, 1e-10f), 1.0f - 1e-10f);
                Hji[rr][c] = lb[i2 * N_SZ + j2] - logf(-logf(u));
            }
        }
    }
    __syncthreads();

    unsigned* kb = keys + (size_t)b * KSTRIDE;
    #pragma unroll
    for (int s = 0; s < 4; ++s) {
        int rr = r + 8 * s;
        int i = i0 + rr, j = j0 + c;
        if (i < N_SZ && j < N_SZ && i <= j) {
            float hji = (ti == tj) ? Hij[c][rr] : Hji[c][rr];
            float sv = 0.5f * ((Hij[rr][c]) + hji);
            int base = i * N_SZ - (i * (i - 1)) / 2;
            kb[base + (j - i)] = sortkey(sv);
        }
    }
}

// -------- kSelW v5: radix select (shfl scans) + bitmask; writes adj + Mg ----
// 1024 threads, 1 block/batch. ~19 barriers. Mask goes to global (1.6 MB tot)
// instead of a 23-MB bf16 tensor.
__global__ __launch_bounds__(1024) void kSelW(
    const unsigned* __restrict__ keys, float* __restrict__ out_base,
    unsigned* __restrict__ Mg)
{
    const int b = blockIdx.x;
    const int tid = threadIdx.x;
    const int lane = tid & 63;
    const int wv = tid >> 6;                        // 0..15
    __shared__ __align__(16) unsigned kl[NUPPER];   // 80.4 KB
    __shared__ unsigned hist[256];
    __shared__ unsigned wtot[16];
    __shared__ unsigned M[N_SZ][7];                 // full-square bitmask, 5.6 KB
    __shared__ unsigned sPrefix;
    __shared__ int sKK;

    // load keys (int4-vectorized; 20100 = 4*5025)
    {
        const int4* kb4 = (const int4*)(keys + (size_t)b * KSTRIDE);
        int4* kl4 = (int4*)kl;
        for (int q = tid; q < 5025; q += 1024) kl4[q] = kb4[q];
    }
    for (int q = tid; q < N_SZ * 7; q += 1024) ((unsigned*)M)[q] = 0;

    unsigned prefix = 0;
    int kk = KSEL;
    for (int round = 0; round < 4; ++round) {
        const int shift = 24 - 8 * round;
        if (tid < 256) hist[tid] = 0;
        __syncthreads();                            // also covers kl loads (round 0)
        for (int idx = tid; idx < NUPPER; idx += 1024) {
            unsigned key = kl[idx];
            bool in = (round == 0) || ((key >> (shift + 8)) == prefix);
            if (in) atomicAdd(&hist[(key >> shift) & 255u], 1u);
        }
        __syncthreads();
        // suffix scan of hist via shfl within waves 0..3 (tid<256)
        unsigned own = 0, v = 0;
        if (tid < 256) {
            own = hist[tid];
            v = own;
            #pragma unroll
            for (int off = 1; off < 64; off <<= 1) {
                unsigned t = __shfl_down(v, off, 64);
                if (lane + off < 64) v += t;
            }
            if (lane == 0) wtot[wv] = v;            // whole-wave sum at lane 0
        }
        __syncthreads();
        if (tid < 256) {
            unsigned add = 0;
            #pragma unroll
            for (int q = 1; q < 4; ++q) if (wv + q < 4) add += wtot[wv + q];
            unsigned sfxv = v + add;                // sum_{u>=tid} hist[u]
            unsigned above = sfxv - own;            // sum_{u>tid}
            if (sfxv >= (unsigned)kk && above < (unsigned)kk) {
                sPrefix = (prefix << 8) | (unsigned)tid;
                sKK = kk - (int)above;
            }
        }
        __syncthreads();
        prefix = sPrefix;
        kk = sKK;
    }
    const unsigned kth = prefix;

    // tie ranking: blocked contiguous ranges (ascending packed == flat order)
    const int lo = tid * 20;
    const int hi = (lo + 20 < NUPPER) ? lo + 20 : NUPPER;
    unsigned mycnt = 0;
    for (int idx = lo; idx < hi; ++idx)
        if (kl[idx] == kth) ++mycnt;
    // inclusive prefix scan via shfl_up + wave-total combine (1 barrier)
    unsigned v = mycnt;
    #pragma unroll
    for (int off = 1; off < 64; off <<= 1) {
        unsigned t = __shfl_up(v, off, 64);
        if (lane >= off) v += t;
    }
    if (lane == 63) wtot[wv] = v;
    __syncthreads();
    unsigned addp = 0;
    for (int q = 0; q < wv; ++q) addp += wtot[q];
    unsigned rank = v + addp - mycnt;               // exclusive prefix

    // decision pass -> bitmask (both triangles)
    if (lo < NUPPER) {
        int iLo = 0, iHi = N_SZ - 1;
        while (iLo < iHi) {
            int mid = (iLo + iHi + 1) >> 1;
            if (rowbase(mid) <= lo) iLo = mid; else iHi = mid - 1;
        }
        int i = iLo;
        int nextBase = rowbase(i + 1);
        for (int idx = lo; idx < hi; ++idx) {
            while (idx >= nextBase) { ++i; nextBase = rowbase(i + 1); }
            unsigned key = kl[idx];
            bool dec;
            if (key > kth) dec = true;
            else if (key == kth) { dec = (rank < (unsigned)kk); ++rank; }
            else dec = false;
            if (dec) {
                int j = i + (idx - rowbase(i));
                atomicOr(&M[i][j >> 5], 1u << (j & 31));
                atomicOr(&M[j][i >> 5], 1u << (i & 31));
            }
        }
    }
    __syncthreads();

    // write fp32 adj -- row-major float4, one broadcast word read per 4 elems
    float* adj = out_base + ADJ_OFF + (size_t)b * NN;
    for (int e = tid; e < 10000; e += 1024) {         // 10000 float4 = 40000
        int i = e / 50;
        int j0 = (e % 50) * 4;
        unsigned wbits = M[i][j0 >> 5] >> (j0 & 31);
        float4 v4;
        v4.x = (wbits & 1u) ? 1.0f : 0.0f;
        v4.y = (wbits & 2u) ? 1.0f : 0.0f;
        v4.z = (wbits & 4u) ? 1.0f : 0.0f;
        v4.w = (wbits & 8u) ? 1.0f : 0.0f;
        *(float4*)(adj + (size_t)i * N_SZ + j0) = v4;
    }
    // write mask rows to global: [200][8] words, coalesced (1600 words/batch)
    unsigned* mb = Mg + (size_t)b * MG_PB;
    for (int e = tid; e < MG_PB; e += 1024) {
        int i = e >> 3, ww = e & 7;
        mb[e] = (ww < 7) ? M[i][ww] : 0u;
    }
}

// -------- K2: XW = x @ w_gnn via bf16 MFMA, barrier-free main loop ----------
__global__ __launch_bounds__(256) void k2_mfma(
    const float* __restrict__ x, const ushort_t* __restrict__ wkg,
    ushort_t* __restrict__ xwm)
{
    const int r0 = blockIdx.x * 64;
    const int tid = threadIdx.x;
    const int w = tid >> 6;
    const int l = tid & 63;
    const int g = l >> 4;
    const int r = l & 15;

    __shared__ __align__(16) ushort_t Cs[64 * 256];   // 32 KB epilogue buffer

    f32x4 acc[4][4];
    #pragma unroll
    for (int mf = 0; mf < 4; ++mf)
        #pragma unroll
        for (int nf = 0; nf < 4; ++nf)
            acc[mf][nf] = (f32x4){0.f, 0.f, 0.f, 0.f};

    for (int c = 0; c < 7; ++c) {
        // k>=200 (chunk 6, g>0): clamp addr; B kgroups 25..27 are zero.
        const int koff = (c * 32 + g * 8 < FIN) ? (c * 32 + g * 8) : 0;
        bf16x8 af[4], bf[4];
        #pragma unroll
        for (int mf = 0; mf < 4; ++mf) {
            const float* ap = x + (size_t)(r0 + mf * 16 + r) * FIN + koff;
            float4 lo = *(const float4*)ap;
            float4 hi = *(const float4*)(ap + 4);
            af[mf] = f2b8(lo, hi);
        }
        #pragma unroll
        for (int nf = 0; nf < 4; ++nf)
            bf[nf] = *(const bf16x8*)(wkg + c * 8192 + g * 2048 + (w * 64 + nf * 16 + r) * 8);
        #pragma unroll
        for (int mf = 0; mf < 4; ++mf)
            #pragma unroll
            for (int nf = 0; nf < 4; ++nf)
                acc[mf][nf] = __builtin_amdgcn_mfma_f32_16x16x32_bf16(
                    af[mf], bf[nf], acc[mf][nf], 0, 0, 0);
    }

    // scatter to Cs in kgroup layout (local rows 0..63)
    #pragma unroll
    for (int mf = 0; mf < 4; ++mf) {
        #pragma unroll
        for (int jj = 0; jj < 4; ++jj) {
            int row = mf * 16 + g * 4 + jj;
            #pragma unroll
            for (int nf = 0; nf < 4; ++nf) {
                int col = w * 64 + nf * 16 + r;
                Cs[((row >> 3) << 11) + col * 8 + (row & 7)] = f2b(acc[mf][nf][jj]);
            }
        }
    }
    __syncthreads();
    // linear write-out: 8 local kgroups (8-row groups never cross batch bound)
    #pragma unroll
    for (int kg = 0; kg < 8; ++kg) {
        int grow0 = r0 + kg * 8;
        int bb = grow0 / N_SZ;
        int jb = grow0 % N_SZ;
        ushort_t* dst = xwm + (size_t)bb * XWM_PB + ((jb >> 3) << 11);
        *(int4*)(dst + tid * 8) = *(const int4*)(Cs + (kg << 11) + tid * 8);
    }
}

// -------- K3 fused v6: A from global bitmask (L2-hot), bit->bf16 in regs ----
// 16-row tiles, 3328 blocks; XCD-bijective: 13 tiles of a batch on one XCD.
__global__ __launch_bounds__(256) void k3_fused(
    const unsigned* __restrict__ Mg, const ushort_t* __restrict__ xwm,
    const float* __restrict__ wl, const float* __restrict__ bl,
    float* __restrict__ out_base)
{
    const int blk = blockIdx.x;
    const int xcd = blk & 7;
    const int idx = blk >> 3;            // 0..415
    const int b = xcd + 8 * (idx / 13);
    const int mt = idx % 13;             // 13 tiles x 16 rows = 208 (>=200 clamp)
    const int tid = threadIdx.x;
    const int w = tid >> 6;
    const int l = tid & 63;
    const int g = l >> 4;
    const int r = l & 15;

    const ushort_t* xwb = xwm + (size_t)b * XWM_PB;

    __shared__ __align__(16) float Es[16 * 256];      // 16 KB; red aliases later
    float (*red)[4][4][8] = (float(*)[4][4][8])Es;    // [w][g][jslot][cls]

    // A-row mask: 8 words (32 B) per lane, L2/L1-hot (6.4 KB per batch)
    int arow = mt * 16 + r; if (arow > N_SZ - 1) arow = N_SZ - 1;
    const int4* mrow = (const int4*)(Mg + (size_t)b * MG_PB + arow * MROW_W);
    int4 m0 = mrow[0];
    int4 m1 = mrow[1];
    unsigned wds[8];
    wds[0] = (unsigned)m0.x; wds[1] = (unsigned)m0.y;
    wds[2] = (unsigned)m0.z; wds[3] = (unsigned)m0.w;
    wds[4] = (unsigned)m1.x; wds[5] = (unsigned)m1.y;
    wds[6] = (unsigned)m1.z; wds[7] = (unsigned)m1.w;

    f32x4 acc[4];
    #pragma unroll
    for (int nf = 0; nf < 4; ++nf) acc[nf] = (f32x4){0.f, 0.f, 0.f, 0.f};

    #pragma unroll
    for (int c = 0; c < 7; ++c) {
        // expand bits g*8..g*8+7 of word c -> bf16x8 (1.0 = 0x3F80)
        unsigned bits = (wds[c] >> (g * 8)) & 0xFFu;
        int dw[4];
        #pragma unroll
        for (int q = 0; q < 4; ++q)
            dw[q] = ((bits >> (2 * q)) & 1u ? 0x3F80 : 0)
                  | ((bits >> (2 * q + 1)) & 1u ? 0x3F800000 : 0);
        int4 ai = {dw[0], dw[1], dw[2], dw[3]};
        bf16x8 af = *(bf16x8*)&ai;

        bf16x8 bf[4];
        // chunk 6, g>0: cols 200..223 -> bits never set (A zero) -> B garbage OK
        #pragma unroll
        for (int nf = 0; nf < 4; ++nf)
            bf[nf] = *(const bf16x8*)(xwb + c * 8192 + g * 2048 + (w * 64 + nf * 16 + r) * 8);
        #pragma unroll
        for (int nf = 0; nf < 4; ++nf)
            acc[nf] = __builtin_amdgcn_mfma_f32_16x16x32_bf16(
                af, bf[nf], acc[nf], 0, 0, 0);
    }

    // ---- phase A: emb -> Es (relu), then coalesced float4 stores ----
    #pragma unroll
    for (int j = 0; j < 4; ++j) {
        int rowl = g * 4 + j;
        #pragma unroll
        for (int nf = 0; nf < 4; ++nf)
            Es[rowl * 256 + w * 64 + nf * 16 + r] = fmaxf(acc[nf][j], 0.0f);
    }
    __syncthreads();
    #pragma unroll
    for (int q = 0; q < 4; ++q) {
        int e = q * 256 + tid;
        int rowl = e >> 6;               // 64 float4 per row
        int c4 = e & 63;
        int grow = mt * 16 + rowl;
        if (grow < N_SZ) {
            float4 v = *(const float4*)(Es + rowl * 256 + c4 * 4);
            *(float4*)(out_base + EMB_OFF + ((size_t)b * N_SZ + grow) * OUT_F + c4 * 4) = v;
        }
    }
    __syncthreads();   // all Es reads done before red overwrites it

    // ---- phase B: out = emb @ w_lin + b (from acc regs) ----
    float wlv[4][NCLS];
    #pragma unroll
    for (int nf = 0; nf < 4; ++nf) {
        int col = w * 64 + nf * 16 + r;
        #pragma unroll
        for (int cls = 0; cls < NCLS; ++cls) wlv[nf][cls] = wl[col * NCLS + cls];
    }
    #pragma unroll
    for (int j = 0; j < 4; ++j) {
        float e0 = fmaxf(acc[0][j], 0.0f);
        float e1 = fmaxf(acc[1][j], 0.0f);
        float e2 = fmaxf(acc[2][j], 0.0f);
        float e3 = fmaxf(acc[3][j], 0.0f);
        float pr[NCLS];
        #pragma unroll
        for (int cls = 0; cls < NCLS; ++cls)
            pr[cls] = e0 * wlv[0][cls] + e1 * wlv[1][cls]
                    + e2 * wlv[2][cls] + e3 * wlv[3][cls];
        #pragma unroll
        for (int off = 1; off <= 8; off <<= 1) {
            #pragma unroll
            for (int cls = 0; cls < NCLS; ++cls)
                pr[cls] += __shfl_xor(pr[cls], off, 64);
        }
        if (r < NCLS) red[w][g][j][r] = pr[r];
    }
    __syncthreads();

    // final combine over waves: 128 outputs (16 rows x 8 cls)
    if (tid < 16 * NCLS) {
        int rowl = tid >> 3, cls = tid & 7;
        int gg = rowl >> 2, jj = rowl & 3;
        int grow = mt * 16 + rowl;
        if (grow < N_SZ) {
            float s = red[0][gg][jj][cls] + red[1][gg][jj][cls]
                    + red[2][gg][jj][cls] + red[3][gg][jj][cls] + bl[cls];
            out_base[((size_t)b * N_SZ + grow) * NCLS + cls] = s;
        }
    }
}

extern "C" void kernel_launch(void* const* d_in, const int* in_sizes, int n_in,
                              void* d_out, int out_size, void* d_ws, size_t ws_size,
                              hipStream_t stream) {
    const float* x    = (const float*)d_in[0];
    const float* gu   = (const float*)d_in[1];
    const float* nets = (const float*)d_in[2];
    const float* wg   = (const float*)d_in[3];
    const float* wl   = (const float*)d_in[4];
    const float* bl   = (const float*)d_in[5];
    const int*   nidx = (const int*)d_in[6];
    float* out = (float*)d_out;

    char* ws = (char*)d_ws;
    unsigned* keys    = (unsigned*)(ws + KEYS_OFF_B);
    ushort_t* xwm     = (ushort_t*)(ws + KEYS_OFF_B);   // aliases keys; k2 after kSelW
    ushort_t* wkg     = (ushort_t*)(ws + WKG_OFF_B);
    unsigned* Mg      = (unsigned*)(ws + MG_OFF_B);

    kA<<<B_SZ * NTILES + 224, 256, 0, stream>>>(gu, nets, nidx, keys, wg, wkg);
    kSelW<<<B_SZ, 1024, 0, stream>>>(keys, out, Mg);
    k2_mfma<<<(B_SZ * N_SZ) / 64, 256, 0, stream>>>(x, wkg, xwm);
    k3_fused<<<B_SZ * 13, 256, 0, stream>>>(Mg, xwm, wl, bl, out);
}